// Round 12
// baseline (337.310 us; speedup 1.0000x reference)
//
#include <hip/hip_runtime.h>
#include <math.h>

#define MTOT 8192   // B*N
#define HD   512    // hidden dim

typedef __attribute__((ext_vector_type(8))) short bf16x8;
typedef __attribute__((ext_vector_type(4))) float floatx4;

__device__ inline unsigned short f2bf(float f) {
    unsigned int u = __float_as_uint(f);
    unsigned int r = (u + 0x7FFFu + ((u >> 16) & 1u)) >> 16;
    return (unsigned short)r;
}
__device__ inline float bf2f(unsigned short h) {
    return __uint_as_float(((unsigned int)h) << 16);
}

// NOTE (r6/r9/r10 lessons): single-block LDS CSR builds and cooperative
// grid.sync variants are 10-40x slower than plain multi-dispatch. grid.sync
// on MI355X costs ~35us each regardless of dirty-set size; a dispatch
// boundary is ~5-10us. The only cheaper-than-boundary trick is merging
// DATA-INDEPENDENT kernels as role planes of one dispatch (done below).

// ---------------- scatter (needs scan done; gat needs scatter -> standalone) ----

__global__ void scatter_edges(const int* __restrict__ src, const int* __restrict__ dst,
                              int* __restrict__ cursor, int* __restrict__ csr_src, int E) {
    int i = blockIdx.x * 256 + threadIdx.x;
    if (i < E) {
        int p = atomicAdd(&cursor[dst[i]], 1);
        csr_src[p] = src[i];
    }
}

// ---------------- prep: weights + activation split + edge count ----------------
// z in [0,6): weight matrix z (32x32 transpose tiles).
// z == 6: activation split. z == 7: count_deg plane (deg pre-zeroed by memset).

__global__ __launch_bounds__(256) void prep_convert(
    const float* __restrict__ W0, const float* __restrict__ W1,
    const float* __restrict__ W2, const float* __restrict__ W3,
    const float* __restrict__ W4, const float* __restrict__ W5,
    unsigned short* __restrict__ wtbase,
    const float* __restrict__ X,
    unsigned short* __restrict__ Ahi, unsigned short* __restrict__ Alo,
    const int* __restrict__ edst, int E, int* __restrict__ deg)
{
    int z = blockIdx.z;
    if (z == 7) {   // count degrees (independent of other planes)
        int t0 = (blockIdx.x * 16 + blockIdx.y) * 256 + threadIdx.x;  // 0..65535
        for (int i = t0; i < E; i += 65536) atomicAdd(&deg[edst[i]], 1);
        return;
    }
    if (z == 6) {   // activation split
        int bid = blockIdx.x * 16 + blockIdx.y;       // 0..255
        int t0 = bid * 256 + threadIdx.x;             // 0..65535
        #pragma unroll
        for (int it = 0; it < 16; ++it) {
            int i = (t0 + it * 65536) * 4;
            float4 vv = *(const float4*)(X + i);
            ushort4 h, l;
            h.x = f2bf(vv.x); l.x = f2bf(vv.x - bf2f(h.x));
            h.y = f2bf(vv.y); l.y = f2bf(vv.y - bf2f(h.y));
            h.z = f2bf(vv.z); l.z = f2bf(vv.z - bf2f(h.z));
            h.w = f2bf(vv.w); l.w = f2bf(vv.w - bf2f(h.w));
            *(ushort4*)(Ahi + i) = h;
            *(ushort4*)(Alo + i) = l;
        }
        return;
    }
    const float* W = (z == 0) ? W0 : (z == 1) ? W1 : (z == 2) ? W2
                   : (z == 3) ? W3 : (z == 4) ? W4 : W5;
    int L = z >> 1, lr = z & 1;
    const size_t SZ = (size_t)HD * HD;
    unsigned short* Whi = wtbase + (L * 4 + lr * 2) * SZ;
    unsigned short* Wlo = Whi + SZ;

    __shared__ float t[32][33];
    int bx = blockIdx.x * 32;  // n base
    int by = blockIdx.y * 32;  // k base
    int tx = threadIdx.x & 31, ty = threadIdx.x >> 5;
    for (int i = ty; i < 32; i += 8)
        t[i][tx] = W[(size_t)(by + i) * HD + bx + tx];
    __syncthreads();
    for (int i = ty; i < 32; i += 8) {
        float vv = t[tx][i];
        unsigned short h = f2bf(vv);
        unsigned short l = f2bf(vv - bf2f(h));
        Whi[(size_t)(bx + i) * HD + by + tx] = h;
        Wlo[(size_t)(bx + i) * HD + by + tx] = l;
    }
}

// ---------------- split-bf16 MFMA dual GEMM (m97 structure) ----------------
// ~31us/dispatch = at the m97-class throughput ceiling for this shape.
// z==2 plane (L0 launch only): one block runs the offs/cursor scan —
// scan needs count (previous dispatch), gemm needs prep; independent roles.

__global__ __launch_bounds__(256) void gemm_mfma_dual(
    const unsigned short* __restrict__ Ahi, const unsigned short* __restrict__ Alo,
    const unsigned short* __restrict__ Bhi_l, const unsigned short* __restrict__ Blo_l,
    const unsigned short* __restrict__ Bhi_r, const unsigned short* __restrict__ Blo_r,
    const float* __restrict__ bias_l, const float* __restrict__ bias_r,
    float* __restrict__ Cl, float* __restrict__ Cr,
    int do_scan, const int* __restrict__ deg,
    int* __restrict__ offs, int* __restrict__ cursor)
{
    if (blockIdx.z == 2) {
        if (do_scan && blockIdx.x == 0 && blockIdx.y == 0) {
            __shared__ int part[256];
            int tid = threadIdx.x;
            int base = tid * 32;
            int v[32]; int s = 0;
            #pragma unroll
            for (int i = 0; i < 32; ++i) { v[i] = deg[base + i]; s += v[i]; }
            part[tid] = s;
            __syncthreads();
            for (int off = 1; off < 256; off <<= 1) {
                int t = (tid >= off) ? part[tid - off] : 0;
                __syncthreads();
                part[tid] += t;
                __syncthreads();
            }
            int run = tid ? part[tid - 1] : 0;
            #pragma unroll
            for (int i = 0; i < 32; ++i) {
                offs[base + i] = run;
                cursor[base + i] = run;
                run += v[i];
            }
            if (tid == 255) offs[MTOT] = run;
        }
        return;
    }

    const unsigned short* Bhi = blockIdx.z ? Bhi_r : Bhi_l;
    const unsigned short* Blo = blockIdx.z ? Blo_r : Blo_l;
    const float* bias         = blockIdx.z ? bias_r : bias_l;
    float* C                  = blockIdx.z ? Cr : Cl;

    __shared__ __align__(16) unsigned short lds[4 * 128 * 32];

    int tid = threadIdx.x;
    int wave = tid >> 6, lane = tid & 63;
    int bm = blockIdx.y * 128, bn = blockIdx.x * 128;

    const unsigned short* gsrc[4] = {Ahi, Alo, Bhi, Blo};
    int rowbase[4] = {bm, bm, bn, bn};

    const unsigned short* gbase =
        gsrc[wave] + (size_t)(rowbase[wave] + (lane >> 2)) * 512 + (lane & 3) * 8;

    floatx4 acc[4][4] = {};

    int wm = wave & 1, wn = wave >> 1;
    int lr = lane & 15, lq = lane >> 4;

    for (int k0 = 0; k0 < 512; k0 += 32) {
        const unsigned short* g = gbase + k0;
        #pragma unroll
        for (int rg = 0; rg < 8; ++rg) {
            __builtin_amdgcn_global_load_lds(
                (const __attribute__((address_space(1))) unsigned int*)(g + (size_t)rg * 16 * 512),
                (__attribute__((address_space(3))) unsigned int*)(&lds[wave * 4096 + rg * 512]),
                16, 0, 0);
        }
        __syncthreads();

        bf16x8 ah[4], al[4], bh[4], bl_[4];
        #pragma unroll
        for (int i = 0; i < 4; ++i) {
            int mrow = wm * 64 + i * 16 + lr;
            ah[i]  = *(const bf16x8*)&lds[0 * 4096 + mrow * 32 + lq * 8];
            al[i]  = *(const bf16x8*)&lds[1 * 4096 + mrow * 32 + lq * 8];
            int nrow = wn * 64 + i * 16 + lr;
            bh[i]  = *(const bf16x8*)&lds[2 * 4096 + nrow * 32 + lq * 8];
            bl_[i] = *(const bf16x8*)&lds[3 * 4096 + nrow * 32 + lq * 8];
        }
        #pragma unroll
        for (int i = 0; i < 4; ++i)
            #pragma unroll
            for (int j = 0; j < 4; ++j) {
                acc[i][j] = __builtin_amdgcn_mfma_f32_16x16x32_bf16(ah[i], bh[j],  acc[i][j], 0, 0, 0);
                acc[i][j] = __builtin_amdgcn_mfma_f32_16x16x32_bf16(ah[i], bl_[j], acc[i][j], 0, 0, 0);
                acc[i][j] = __builtin_amdgcn_mfma_f32_16x16x32_bf16(al[i], bh[j],  acc[i][j], 0, 0, 0);
            }
        __syncthreads();
    }

    #pragma unroll
    for (int j = 0; j < 4; ++j) {
        int n = bn + wn * 64 + j * 16 + lr;
        float bv = bias[n];
        #pragma unroll
        for (int i = 0; i < 4; ++i) {
            int mbase = bm + wm * 64 + i * 16 + lq * 4;
            #pragma unroll
            for (int r = 0; r < 4; ++r)
                C[(size_t)(mbase + r) * 512 + n] = acc[i][j][r] + bv;
        }
    }
}

// ---------------- fused aggregation v3 (unchanged from r11) ----------------
// Block = 512 thr (8 waves) per 4 nodes, XCD-swizzled (graph g -> XCD g).
// CSR idx preloaded to LDS; lrelu via a·lrelu(t) = 0.6·Σa·t + 0.4·Σa·|t|.

__global__ __launch_bounds__(512) void gat_fused3(
    const float* __restrict__ xl, const float* __restrict__ xr,
    const float* __restrict__ avec, const float* __restrict__ bias,
    const int* __restrict__ offs, const int* __restrict__ csr_src,
    float* __restrict__ out, unsigned short* __restrict__ Ohi,
    unsigned short* __restrict__ Olo, int write_fp32)
{
    __shared__ float xr_sh[4][512];   // 8 KB
    __shared__ float sc_sh[4][128];   // 2 KB
    __shared__ int   idx_sh[4][128];  // 2 KB
    __shared__ float inv_sh[4];

    int gid = blockIdx.x;
    int nbase = ((gid & 7) << 10) + ((gid >> 3) << 2);
    int tid = threadIdx.x;
    int wv = tid >> 6, lane = tid & 63;

    int o0 = offs[nbase], o1 = offs[nbase + 1], o2 = offs[nbase + 2];
    int o3 = offs[nbase + 3], o4 = offs[nbase + 4];

    {
        int row = tid >> 7, col = tid & 127;
        *(float4*)&xr_sh[row][col * 4] =
            *(const float4*)(xr + (size_t)(nbase + row) * HD + col * 4);
    }
    if (wv < 4) {
        int nb = (wv == 0) ? o0 : (wv == 1) ? o1 : (wv == 2) ? o2 : o3;
        int ne = (wv == 0) ? o1 : (wv == 1) ? o2 : (wv == 2) ? o3 : o4;
        int dg = ne - nb; if (dg > 128) dg = 128;
        for (int i = lane; i < dg; i += 64) idx_sh[wv][i] = csr_src[nb + i];
    }
    __syncthreads();

    {
        int sub = lane >> 4, flane = lane & 15;
        float4 av[8];
        #pragma unroll
        for (int i = 0; i < 8; ++i)
            av[i] = *(const float4*)(avec + i * 64 + flane * 4);

        for (int p0 = o0 + wv * 4; p0 < o4; p0 += 32) {
            int p = p0 + sub;
            bool valid = p < o4;
            int pc = valid ? p : o0;
            int nid = (pc >= o1) + (pc >= o2) + (pc >= o3);
            int nb = (nid == 0) ? o0 : (nid == 1) ? o1 : (nid == 2) ? o2 : o3;
            int local = pc - nb;
            valid = valid && (local < 128);
            int j = idx_sh[nid][valid ? local : 0];
            const float* xls = xl + (size_t)j * HD;
            float pe0 = 0.f, pe1 = 0.f;
            #pragma unroll
            for (int i = 0; i < 8; ++i) {
                float4 xv = *(const float4*)(xls + i * 64 + flane * 4);
                float4 rv = *(const float4*)&xr_sh[nid][i * 64 + flane * 4];
                float t;
                t = xv.x + rv.x; pe0 = fmaf(av[i].x, t, pe0); pe1 = fmaf(av[i].x, fabsf(t), pe1);
                t = xv.y + rv.y; pe0 = fmaf(av[i].y, t, pe0); pe1 = fmaf(av[i].y, fabsf(t), pe1);
                t = xv.z + rv.z; pe0 = fmaf(av[i].z, t, pe0); pe1 = fmaf(av[i].z, fabsf(t), pe1);
                t = xv.w + rv.w; pe0 = fmaf(av[i].w, t, pe0); pe1 = fmaf(av[i].w, fabsf(t), pe1);
            }
            float pe = fmaf(0.6f, pe0, 0.4f * pe1);   // == a . leaky_relu(., 0.2)
            pe += __shfl_xor(pe, 1, 64);
            pe += __shfl_xor(pe, 2, 64);
            pe += __shfl_xor(pe, 4, 64);
            pe += __shfl_xor(pe, 8, 64);
            if (valid && flane == 0) sc_sh[nid][local] = pe;
        }
    }
    __syncthreads();

    if (wv < 4) {
        int nb = (wv == 0) ? o0 : (wv == 1) ? o1 : (wv == 2) ? o2 : o3;
        int ne = (wv == 0) ? o1 : (wv == 1) ? o2 : (wv == 2) ? o3 : o4;
        int dg = ne - nb; if (dg > 128) dg = 128;
        float s0v = (lane < dg) ? sc_sh[wv][lane] : -1e30f;
        float s1v = (lane + 64 < dg) ? sc_sh[wv][lane + 64] : -1e30f;
        float m = fmaxf(s0v, s1v);
        #pragma unroll
        for (int off = 32; off; off >>= 1) m = fmaxf(m, __shfl_xor(m, off, 64));
        float e0 = (lane < dg) ? __expf(s0v - m) : 0.f;
        float e1 = (lane + 64 < dg) ? __expf(s1v - m) : 0.f;
        if (lane < dg) sc_sh[wv][lane] = e0;
        if (lane + 64 < dg) sc_sh[wv][lane + 64] = e1;
        float s = e0 + e1;
        #pragma unroll
        for (int off = 32; off; off >>= 1) s += __shfl_xor(s, off, 64);
        if (lane == 0) inv_sh[wv] = (s > 0.f) ? 1.f / s : 0.f;
    }
    __syncthreads();

    int nid = wv & 3, half = wv >> 2;
    int node = nbase + nid;
    int nb = (nid == 0) ? o0 : (nid == 1) ? o1 : (nid == 2) ? o2 : o3;
    int ne = (nid == 0) ? o1 : (nid == 1) ? o2 : (nid == 2) ? o3 : o4;
    int dg = ne - nb; if (dg > 128) dg = 128;
    int hb = half * 256 + lane * 4;

    float4 acc = {0.f, 0.f, 0.f, 0.f};
    int p = 0;
    for (; p + 8 <= dg; p += 8) {
        float w[8]; const float* q[8];
        #pragma unroll
        for (int u = 0; u < 8; ++u) {
            w[u] = sc_sh[nid][p + u];
            q[u] = xl + (size_t)idx_sh[nid][p + u] * HD + hb;
        }
        float4 x[8];
        #pragma unroll
        for (int u = 0; u < 8; ++u) x[u] = *(const float4*)q[u];
        #pragma unroll
        for (int u = 0; u < 8; ++u) {
            acc.x += w[u] * x[u].x; acc.y += w[u] * x[u].y;
            acc.z += w[u] * x[u].z; acc.w += w[u] * x[u].w;
        }
    }
    for (; p < dg; ++p) {
        float w = sc_sh[nid][p];
        const float* q = xl + (size_t)idx_sh[nid][p] * HD + hb;
        float4 x = *(const float4*)q;
        acc.x += w * x.x; acc.y += w * x.y; acc.z += w * x.z; acc.w += w * x.w;
    }

    float inv = inv_sh[nid];
    float4 bv = *(const float4*)(bias + hb);
    float4 o = {acc.x * inv + bv.x, acc.y * inv + bv.y,
                acc.z * inv + bv.z, acc.w * inv + bv.w};

    if (write_fp32) {
        *(float4*)(out + (size_t)node * HD + hb) = o;
    } else {
        size_t rb = (size_t)node * HD + hb;
        ushort4 h, lo;
        h.x = f2bf(o.x); lo.x = f2bf(o.x - bf2f(h.x));
        h.y = f2bf(o.y); lo.y = f2bf(o.y - bf2f(h.y));
        h.z = f2bf(o.z); lo.z = f2bf(o.z - bf2f(h.z));
        h.w = f2bf(o.w); lo.w = f2bf(o.w - bf2f(h.w));
        *(ushort4*)(Ohi + rb) = h;
        *(ushort4*)(Olo + rb) = lo;
    }
}

// ---------------- launch ----------------
// 8 kernel dispatches + 1 memset (was 10 kernels):
//   memset(deg) ; prep(+count) ; gemm0(+scan) ; scatter ; gat0 ;
//   gemm1 ; gat1 ; gemm2 ; gat2

extern "C" void kernel_launch(void* const* d_in, const int* in_sizes, int n_in,
                              void* d_out, int out_size, void* d_ws, size_t ws_size,
                              hipStream_t stream) {
    const float* x0 = (const float*)d_in[0];
    const int* eidx = (const int*)d_in[2];
    int E = in_sizes[2] / 2;
    const int* esrc = eidx;
    const int* edst = eidx + E;

    const float* Wl[3] = {(const float*)d_in[3],  (const float*)d_in[9],  (const float*)d_in[15]};
    const float* bl[3] = {(const float*)d_in[4],  (const float*)d_in[10], (const float*)d_in[16]};
    const float* Wr[3] = {(const float*)d_in[5],  (const float*)d_in[11], (const float*)d_in[17]};
    const float* br[3] = {(const float*)d_in[6],  (const float*)d_in[12], (const float*)d_in[18]};
    const float* av[3] = {(const float*)d_in[7],  (const float*)d_in[13], (const float*)d_in[19]};
    const float* bs[3] = {(const float*)d_in[8],  (const float*)d_in[14], (const float*)d_in[20]};

    char* w = (char*)d_ws;
    unsigned short* Ahi = (unsigned short*)w; w += (size_t)MTOT * HD * 2;
    unsigned short* Alo = (unsigned short*)w; w += (size_t)MTOT * HD * 2;
    unsigned short* wtbase = (unsigned short*)w; w += 12 * (size_t)HD * HD * 2;
    float* xl = (float*)w; w += (size_t)MTOT * HD * 4;
    float* xr = (float*)w; w += (size_t)MTOT * HD * 4;
    int* deg    = (int*)w;
    int* offs   = deg + MTOT;
    int* cursor = offs + MTOT + 8;
    int* csr    = cursor + MTOT;
    const size_t SZ = (size_t)HD * HD;

    hipMemsetAsync(deg, 0, MTOT * sizeof(int), stream);

    prep_convert<<<dim3(16, 16, 8), 256, 0, stream>>>(
        Wl[0], Wr[0], Wl[1], Wr[1], Wl[2], Wr[2], wtbase, x0, Ahi, Alo,
        edst, E, deg);

    for (int L = 0; L < 3; ++L) {
        int first = (L == 0);
        dim3 ggrid(HD / 128, MTOT / 128, first ? 3 : 2);
        gemm_mfma_dual<<<ggrid, 256, 0, stream>>>(Ahi, Alo,
            wtbase + (L * 4 + 0) * SZ, wtbase + (L * 4 + 1) * SZ,
            wtbase + (L * 4 + 2) * SZ, wtbase + (L * 4 + 3) * SZ,
            bl[L], br[L], xl, xr,
            first, deg, offs, cursor);
        if (first)
            scatter_edges<<<(E + 255) / 256, 256, 0, stream>>>(esrc, edst, cursor, csr, E);
        int last = (L == 2);
        gat_fused3<<<MTOT / 4, 512, 0, stream>>>(xl, xr, av[L], bs[L], offs, csr,
                                                 last ? (float*)d_out : nullptr,
                                                 last ? nullptr : Ahi,
                                                 last ? nullptr : Alo,
                                                 last);
    }
}